// Round 1
// baseline (461.416 us; speedup 1.0000x reference)
//
#include <hip/hip_runtime.h>
#include <math.h>

// Problem constants (from reference): B=2, L=512, C=768, C/3=256, pairDim=128
// mean_out / mean_trans stored in ws as [B,32,L,64] f32 (8 MB each)

__global__ __launch_bounds__(256) void k1_rowstage(
    const float* __restrict__ x, const float* __restrict__ ln_w, const float* __restrict__ ln_b,
    const float* __restrict__ W1, const float* __restrict__ b1,
    const float* __restrict__ Wa, const float* __restrict__ ba,
    float* __restrict__ mo_g, float* __restrict__ mt_g)
{
    const int bl  = blockIdx.x;          // b*512 + l
    const int tid = threadIdx.x;
    const int b   = bl >> 9;
    const int l   = bl & 511;

    __shared__ float hs[768];
    __shared__ float ts[768];
    __shared__ float mos[2048];
    __shared__ float was[64 * 65];       // Wa padded stride 65 (bank-conflict-free)
    __shared__ float ws1[4], ws2[4];

    const float* xrow = x + (size_t)bl * 768;
    float v0 = xrow[tid], v1 = xrow[tid + 256], v2 = xrow[tid + 512];

    // stage Wa (64x64) with +1 pad
    #pragma unroll
    for (int i = 0; i < 16; i++) {
        int idx = i * 256 + tid;
        was[(idx >> 6) * 65 + (idx & 63)] = Wa[idx];
    }

    // LayerNorm stats (block reduce over 768)
    float s1 = v0 + v1 + v2;
    float s2 = v0 * v0 + v1 * v1 + v2 * v2;
    #pragma unroll
    for (int off = 32; off > 0; off >>= 1) {
        s1 += __shfl_down(s1, off);
        s2 += __shfl_down(s2, off);
    }
    if ((tid & 63) == 0) { ws1[tid >> 6] = s1; ws2[tid >> 6] = s2; }
    __syncthreads();
    float tot1 = ws1[0] + ws1[1] + ws1[2] + ws1[3];
    float tot2 = ws2[0] + ws2[1] + ws2[2] + ws2[3];
    float mu   = tot1 * (1.0f / 768.0f);
    float var  = tot2 * (1.0f / 768.0f) - mu * mu;
    float rstd = rsqrtf(var + 1e-6f);

    hs[tid]       = (v0 - mu) * rstd * ln_w[tid]       + ln_b[tid];
    hs[tid + 256] = (v1 - mu) * rstd * ln_w[tid + 256] + ln_b[tid + 256];
    hs[tid + 512] = (v2 - mu) * rstd * ln_w[tid + 512] + ln_b[tid + 512];
    __syncthreads();

    // t[k][j] = h[k] . W1[j,:] + b1[j], j = tid, k = 0..2
    {
        float a0 = 0.f, a1 = 0.f, a2 = 0.f;
        const float4* wrow = (const float4*)(W1 + (size_t)tid * 256);
        const float4* h0 = (const float4*)(hs);
        const float4* h1 = (const float4*)(hs + 256);
        const float4* h2 = (const float4*)(hs + 512);
        #pragma unroll 8
        for (int i4 = 0; i4 < 64; i4++) {
            float4 w = wrow[i4];
            float4 x0 = h0[i4], x1 = h1[i4], x2 = h2[i4];
            a0 += x0.x * w.x + x0.y * w.y + x0.z * w.z + x0.w * w.w;
            a1 += x1.x * w.x + x1.y * w.y + x1.z * w.z + x1.w * w.w;
            a2 += x2.x * w.x + x2.y * w.y + x2.z * w.z + x2.w * w.w;
        }
        float bb = b1[tid];
        ts[tid]       = a0 + bb;
        ts[tid + 256] = a1 + bb;
        ts[tid + 512] = a2 + bb;
    }
    __syncthreads();

    // mean_out[c][i*8+j] = sum_k t[k][c*8+i]*t[k][c*8+j] / 3
    {
        const int c = tid >> 3, i = tid & 7;
        float ti0 = ts[c * 8 + i], ti1 = ts[256 + c * 8 + i], ti2 = ts[512 + c * 8 + i];
        float mo8[8];
        #pragma unroll
        for (int j = 0; j < 8; j++) {
            mo8[j] = (ti0 * ts[c * 8 + j] + ti1 * ts[256 + c * 8 + j] + ti2 * ts[512 + c * 8 + j]) * (1.0f / 3.0f);
            mos[c * 64 + i * 8 + j] = mo8[j];
        }
        size_t mobase = ((size_t)(b * 32 + c) * 512 + l) * 64 + i * 8;
        *(float4*)(mo_g + mobase)     = make_float4(mo8[0], mo8[1], mo8[2], mo8[3]);
        *(float4*)(mo_g + mobase + 4) = make_float4(mo8[4], mo8[5], mo8[6], mo8[7]);
    }
    __syncthreads();

    // mean_trans[c][d] = gelu( mean_out[c,:] . Wa[d,:] + ba[d] )
    {
        const int d = tid & 63, cg = tid >> 6;   // wave-uniform c -> mos reads broadcast
        float ber = ba[d];
        #pragma unroll
        for (int cc = 0; cc < 8; cc++) {
            int c2 = cg + cc * 4;
            const float* mrow = &mos[c2 * 64];
            float acc = ber;
            #pragma unroll 16
            for (int e = 0; e < 64; e++) acc += mrow[e] * was[d * 65 + e];
            float g = 0.5f * acc * (1.0f + erff(acc * 0.70710678118654752f));
            mt_g[((size_t)(b * 32 + c2) * 512 + l) * 64 + d] = g;
        }
    }
}

// k2: per 32x32 (l,m) tile: raw[c][l][m] = MO[c,l,:].MT[c,m,:]  (phase A, LDS-parked)
//     then out[l,m,p] = sum_c raw * W2[p,c] + b2[p]             (phase B, coalesced stores)
__global__ __launch_bounds__(256) void k2_pair(
    const float* __restrict__ mo_g, const float* __restrict__ mt_g,
    const float* __restrict__ W2, const float* __restrict__ b2,
    float* __restrict__ out)
{
    __shared__ float smo[32 * 68];           // stride 68: 16B-aligned rows, conflict-light
    __shared__ float smt[32 * 68];
    __shared__ float raw2[1024 * 34];        // [pair][c], stride 34 (8B-aligned rows)

    const int tid = threadIdx.x;
    const int b  = blockIdx.z;
    const int l0 = blockIdx.x << 5;
    const int m0 = blockIdx.y << 5;
    const int ty = tid >> 4, tx = tid & 15;
    const int r0 = 2 * ty, q0 = 2 * tx;

    // W2 row for this lane's p (phase B), held in VGPRs
    float w2r[32];
    {
        const float4* w2row = (const float4*)(W2 + (size_t)(tid & 127) * 32);
        #pragma unroll
        for (int q = 0; q < 8; q++) {
            float4 v = w2row[q];
            w2r[4 * q] = v.x; w2r[4 * q + 1] = v.y; w2r[4 * q + 2] = v.z; w2r[4 * q + 3] = v.w;
        }
    }
    const float b2r = b2[tid & 127];

    for (int c = 0; c < 32; c++) {
        __syncthreads();
        {
            const float4* smo_src = (const float4*)(mo_g + (((size_t)(b * 32 + c) * 512) + l0) * 64);
            const float4* smt_src = (const float4*)(mt_g + (((size_t)(b * 32 + c) * 512) + m0) * 64);
            #pragma unroll
            for (int rep = 0; rep < 2; rep++) {
                int f4 = tid + rep * 256;            // 0..511 float4s = 32 rows x 16
                int row = f4 >> 4, c4 = f4 & 15;
                *(float4*)&smo[row * 68 + 4 * c4] = smo_src[f4];
                *(float4*)&smt[row * 68 + 4 * c4] = smt_src[f4];
            }
        }
        __syncthreads();

        float acc00 = 0.f, acc01 = 0.f, acc10 = 0.f, acc11 = 0.f;
        const float4* A0 = (const float4*)&smo[r0 * 68];
        const float4* A1 = (const float4*)&smo[(r0 + 1) * 68];
        const float4* T0 = (const float4*)&smt[q0 * 68];
        const float4* T1 = (const float4*)&smt[(q0 + 1) * 68];
        #pragma unroll
        for (int d4 = 0; d4 < 16; d4++) {
            float4 a0 = A0[d4], a1 = A1[d4], t0 = T0[d4], t1 = T1[d4];
            acc00 += a0.x * t0.x + a0.y * t0.y + a0.z * t0.z + a0.w * t0.w;
            acc01 += a0.x * t1.x + a0.y * t1.y + a0.z * t1.z + a0.w * t1.w;
            acc10 += a1.x * t0.x + a1.y * t0.y + a1.z * t0.z + a1.w * t0.w;
            acc11 += a1.x * t1.x + a1.y * t1.y + a1.z * t1.z + a1.w * t1.w;
        }
        raw2[(r0 * 32 + q0) * 34 + c]           = acc00;
        raw2[(r0 * 32 + q0 + 1) * 34 + c]       = acc01;
        raw2[((r0 + 1) * 32 + q0) * 34 + c]     = acc10;
        raw2[((r0 + 1) * 32 + q0 + 1) * 34 + c] = acc11;
    }
    __syncthreads();

    // phase B: lane owns p = tid&127; raw rows are wave-uniform broadcasts
    const int p = tid & 127;
    const int half = tid >> 7;
    size_t outbase = (((size_t)b * 512 + l0) * 512 + m0) * 128 + p;
    #pragma unroll 4
    for (int pr = half; pr < 1024; pr += 2) {
        const float2* rr = (const float2*)&raw2[pr * 34];
        float acc = b2r;
        #pragma unroll
        for (int c2 = 0; c2 < 16; c2++) {
            float2 v = rr[c2];
            acc += v.x * w2r[2 * c2] + v.y * w2r[2 * c2 + 1];
        }
        int ll = pr >> 5, mm = pr & 31;
        out[outbase + ((size_t)ll * 512 + mm) * 128] = acc;
    }
}

extern "C" void kernel_launch(void* const* d_in, const int* in_sizes, int n_in,
                              void* d_out, int out_size, void* d_ws, size_t ws_size,
                              hipStream_t stream) {
    const float* x    = (const float*)d_in[0];
    const float* ln_w = (const float*)d_in[1];
    const float* ln_b = (const float*)d_in[2];
    const float* W1   = (const float*)d_in[3];
    const float* b1   = (const float*)d_in[4];
    const float* Wa   = (const float*)d_in[5];
    const float* ba   = (const float*)d_in[6];
    const float* W2   = (const float*)d_in[7];
    const float* b2   = (const float*)d_in[8];
    float* out = (float*)d_out;

    float* mo = (float*)d_ws;                          // [2,32,512,64] = 8 MB
    float* mt = mo + (size_t)2 * 32 * 512 * 64;        // [2,32,512,64] = 8 MB

    k1_rowstage<<<1024, 256, 0, stream>>>(x, ln_w, ln_b, W1, b1, Wa, ba, mo, mt);
    k2_pair<<<dim3(16, 16, 2), 256, 0, stream>>>(mo, mt, W2, b2, out);
}

// Round 2
// 111.892 us; speedup vs baseline: 4.1237x; 4.1237x over previous
//
#include <hip/hip_runtime.h>
#include <math.h>

// B=2, L=512, C=768, C/3=256, pairDim=128
// mo/mt stored in ws as [B,32,L,64] _Float16 (4 MB each)

typedef __attribute__((ext_vector_type(8))) _Float16 half8;
typedef __attribute__((ext_vector_type(4))) float f32x4;

#define MFMA_F16(a,b,c) __builtin_amdgcn_mfma_f32_16x16x32_f16((a),(b),(c),0,0,0)

static __device__ inline unsigned pack2f16(float a, float b) {
    _Float16 ha = (_Float16)a, hb = (_Float16)b;
    unsigned short ua = __builtin_bit_cast(unsigned short, ha);
    unsigned short ub = __builtin_bit_cast(unsigned short, hb);
    return (unsigned)ua | ((unsigned)ub << 16);
}

__global__ __launch_bounds__(256) void k1_rowstage(
    const float* __restrict__ x, const float* __restrict__ ln_w, const float* __restrict__ ln_b,
    const float* __restrict__ W1, const float* __restrict__ b1,
    const float* __restrict__ Wa, const float* __restrict__ ba,
    _Float16* __restrict__ mo_g, _Float16* __restrict__ mt_g)
{
    const int bl  = blockIdx.x;          // b*512 + l
    const int tid = threadIdx.x;
    const int b   = bl >> 9;
    const int l   = bl & 511;

    __shared__ float hs[768];
    __shared__ float ts[768];
    __shared__ float mos[2048];
    __shared__ float was[64 * 65];       // Wa padded stride 65
    __shared__ float ws1[4], ws2[4];

    const float* xrow = x + (size_t)bl * 768;
    float v0 = xrow[tid], v1 = xrow[tid + 256], v2 = xrow[tid + 512];

    #pragma unroll
    for (int i = 0; i < 16; i++) {
        int idx = i * 256 + tid;
        was[(idx >> 6) * 65 + (idx & 63)] = Wa[idx];
    }

    float s1 = v0 + v1 + v2;
    float s2 = v0 * v0 + v1 * v1 + v2 * v2;
    #pragma unroll
    for (int off = 32; off > 0; off >>= 1) {
        s1 += __shfl_down(s1, off);
        s2 += __shfl_down(s2, off);
    }
    if ((tid & 63) == 0) { ws1[tid >> 6] = s1; ws2[tid >> 6] = s2; }
    __syncthreads();
    float tot1 = ws1[0] + ws1[1] + ws1[2] + ws1[3];
    float tot2 = ws2[0] + ws2[1] + ws2[2] + ws2[3];
    float mu   = tot1 * (1.0f / 768.0f);
    float var  = tot2 * (1.0f / 768.0f) - mu * mu;
    float rstd = rsqrtf(var + 1e-6f);

    hs[tid]       = (v0 - mu) * rstd * ln_w[tid]       + ln_b[tid];
    hs[tid + 256] = (v1 - mu) * rstd * ln_w[tid + 256] + ln_b[tid + 256];
    hs[tid + 512] = (v2 - mu) * rstd * ln_w[tid + 512] + ln_b[tid + 512];
    __syncthreads();

    {
        float a0 = 0.f, a1 = 0.f, a2 = 0.f;
        const float4* wrow = (const float4*)(W1 + (size_t)tid * 256);
        const float4* h0 = (const float4*)(hs);
        const float4* h1 = (const float4*)(hs + 256);
        const float4* h2 = (const float4*)(hs + 512);
        #pragma unroll 8
        for (int i4 = 0; i4 < 64; i4++) {
            float4 w = wrow[i4];
            float4 x0 = h0[i4], x1 = h1[i4], x2 = h2[i4];
            a0 += x0.x * w.x + x0.y * w.y + x0.z * w.z + x0.w * w.w;
            a1 += x1.x * w.x + x1.y * w.y + x1.z * w.z + x1.w * w.w;
            a2 += x2.x * w.x + x2.y * w.y + x2.z * w.z + x2.w * w.w;
        }
        float bb = b1[tid];
        ts[tid]       = a0 + bb;
        ts[tid + 256] = a1 + bb;
        ts[tid + 512] = a2 + bb;
    }
    __syncthreads();

    {
        const int c = tid >> 3, i = tid & 7;
        float ti0 = ts[c * 8 + i], ti1 = ts[256 + c * 8 + i], ti2 = ts[512 + c * 8 + i];
        half8 h8;
        #pragma unroll
        for (int j = 0; j < 8; j++) {
            float m = (ti0 * ts[c * 8 + j] + ti1 * ts[256 + c * 8 + j] + ti2 * ts[512 + c * 8 + j]) * (1.0f / 3.0f);
            mos[c * 64 + i * 8 + j] = m;
            h8[j] = (_Float16)m;
        }
        size_t mobase = ((size_t)(b * 32 + c) * 512 + l) * 64 + i * 8;
        *(half8*)(mo_g + mobase) = h8;
    }
    __syncthreads();

    {
        const int d = tid & 63, cg = tid >> 6;
        float ber = ba[d];
        #pragma unroll
        for (int cc = 0; cc < 8; cc++) {
            int c2 = cg + cc * 4;
            const float* mrow = &mos[c2 * 64];
            float acc = ber;
            #pragma unroll 16
            for (int e = 0; e < 64; e++) acc += mrow[e] * was[d * 65 + e];
            float g = 0.5f * acc * (1.0f + erff(acc * 0.70710678118654752f));
            mt_g[((size_t)(b * 32 + c2) * 512 + l) * 64 + d] = (_Float16)g;
        }
    }
}

// k2: per (32 l x 16 m) tile:
//   phase A (MFMA): raw[pair][c] = MO[c,l,:].MT[c,m,:]  -> f16 in LDS (pad 40, XOR-swizzled)
//   phase B (MFMA): out[l,m,p] = raw[pair,:].W2[p,:] + b2[p]
__global__ __launch_bounds__(256, 4) void k2_mfma(
    const _Float16* __restrict__ mo, const _Float16* __restrict__ mt,
    const float* __restrict__ W2, const float* __restrict__ b2,
    float* __restrict__ out)
{
    __shared__ _Float16 raw16[512 * 40];   // [pair][c], 80B rows (16B aligned), 40 KB

    const int tid  = threadIdx.x;
    const int w    = tid >> 6;
    const int lane = tid & 63;
    const int lr   = lane & 15;
    const int lk   = lane >> 4;
    const int b    = blockIdx.z;
    const int m0   = blockIdx.x << 4;     // 32 m-tiles
    const int l0   = blockIdx.y << 5;     // 16 l-tiles

    // W2 fragments (NT: W2 is [128][32] = N x K row-major) + b2, held in VGPRs
    half8 wfrag[8]; float b2v[8];
    #pragma unroll
    for (int c8 = 0; c8 < 8; ++c8) {
        int p = c8 * 16 + lr;
        const float* wp = W2 + (size_t)p * 32 + lk * 8;
        float4 u = *(const float4*)wp;
        float4 v = *(const float4*)(wp + 4);
        half8 f;
        f[0] = (_Float16)u.x; f[1] = (_Float16)u.y; f[2] = (_Float16)u.z; f[3] = (_Float16)u.w;
        f[4] = (_Float16)v.x; f[5] = (_Float16)v.y; f[6] = (_Float16)v.z; f[7] = (_Float16)v.w;
        wfrag[c8] = f;
        b2v[c8] = b2[p];
    }

    // ---- phase A: wave w computes c in [8w, 8w+8), all 512 pairs ----
    #pragma unroll
    for (int cp = 0; cp < 4; ++cp) {
        const int c0 = w * 8 + cp * 2;
        f32x4 acc[2][2] = {};   // [ci][rh]
        #pragma unroll
        for (int ci = 0; ci < 2; ++ci) {
            const int c = c0 + ci;
            const _Float16* mo_c = mo + (((size_t)(b * 32 + c) * 512) + l0) * 64;
            const _Float16* mt_c = mt + (((size_t)(b * 32 + c) * 512) + m0) * 64;
            #pragma unroll
            for (int ks = 0; ks < 2; ++ks) {
                half8 bfrag = *(const half8*)(mt_c + (size_t)lr * 64 + ks * 32 + lk * 8);
                #pragma unroll
                for (int rh = 0; rh < 2; ++rh) {
                    half8 afrag = *(const half8*)(mo_c + (size_t)(rh * 16 + lr) * 64 + ks * 32 + lk * 8);
                    acc[ci][rh] = MFMA_F16(afrag, bfrag, acc[ci][rh]);
                }
            }
        }
        // park raw tile: pair = l_local*16 + m_local; D layout: row(l)=lk*4+j, col(m)=lr
        #pragma unroll
        for (int rh = 0; rh < 2; ++rh) {
            #pragma unroll
            for (int j = 0; j < 4; ++j) {
                int pair = (rh * 16 + lk * 4 + j) * 16 + lr;
                int sw   = (((pair >> 3) & 1) << 3) | (((pair >> 6) & 1) << 4);
                *(unsigned*)&raw16[pair * 40 + (c0 ^ sw)] = pack2f16(acc[0][rh][j], acc[1][rh][j]);
            }
        }
    }
    __syncthreads();

    // ---- phase B: wave w handles row-frags r in [8w, 8w+8) (r == l_local) ----
    #pragma unroll
    for (int i = 0; i < 8; ++i) {
        const int r  = w * 8 + i;
        const int pr = r * 16 + lr;
        const int swr = (((pr >> 3) & 1) << 3) | (((pr >> 6) & 1) << 4);
        half8 a = *(const half8*)&raw16[pr * 40 + ((lk * 8) ^ swr)];
        size_t ob = (((size_t)(b * 512 + l0 + r)) * 512 + m0 + lk * 4) * 128 + lr;
        #pragma unroll
        for (int c8 = 0; c8 < 8; ++c8) {
            f32x4 d = { b2v[c8], b2v[c8], b2v[c8], b2v[c8] };
            d = MFMA_F16(a, wfrag[c8], d);
            #pragma unroll
            for (int j = 0; j < 4; ++j)
                out[ob + (size_t)j * 128 + c8 * 16] = d[j];
        }
    }
}

extern "C" void kernel_launch(void* const* d_in, const int* in_sizes, int n_in,
                              void* d_out, int out_size, void* d_ws, size_t ws_size,
                              hipStream_t stream) {
    const float* x    = (const float*)d_in[0];
    const float* ln_w = (const float*)d_in[1];
    const float* ln_b = (const float*)d_in[2];
    const float* W1   = (const float*)d_in[3];
    const float* b1   = (const float*)d_in[4];
    const float* Wa   = (const float*)d_in[5];
    const float* ba   = (const float*)d_in[6];
    const float* W2   = (const float*)d_in[7];
    const float* b2   = (const float*)d_in[8];
    float* out = (float*)d_out;

    _Float16* mo = (_Float16*)d_ws;                     // [2,32,512,64] f16 = 4 MB
    _Float16* mt = mo + (size_t)2 * 32 * 512 * 64;      // [2,32,512,64] f16 = 4 MB

    k1_rowstage<<<1024, 256, 0, stream>>>(x, ln_w, ln_b, W1, b1, Wa, ba, mo, mt);
    k2_mfma<<<dim3(32, 16, 2), 256, 0, stream>>>(mo, mt, W2, b2, out);
}